// Round 1
// baseline (617.399 us; speedup 1.0000x reference)
//
#include <hip/hip_runtime.h>
#include <hip/hip_bf16.h>

#define N_NODES 100000
#define N_EDGES 800000
#define FEATS   128
#define OHEAD   128
#define CAP     64

// ---------------- Kernel 1: fused projections -----------------------------
// C[N,128] = feats[N,128] @ W + b  for W in {Wq,Wk,Wv,Wffn} (blockIdx.y)
// block: 256 threads, tile 64 rows x 128 cols, per-thread 4x8.
__global__ __launch_bounds__(256) void proj_kernel(
    const float* __restrict__ feats,
    const float* __restrict__ Wq, const float* __restrict__ bq,
    const float* __restrict__ Wk, const float* __restrict__ bk,
    const float* __restrict__ Wv, const float* __restrict__ bv,
    const float* __restrict__ Wf, const float* __restrict__ bf,
    float* __restrict__ q, float* __restrict__ k, float* __restrict__ v,
    float* __restrict__ h0)
{
    __shared__ float As[64][132];   // +4 pad: conflict-free column reads
    const float* W; const float* b; float* out;
    switch (blockIdx.y) {
        case 0:  W = Wq; b = bq; out = q;  break;
        case 1:  W = Wk; b = bk; out = k;  break;
        case 2:  W = Wv; b = bv; out = v;  break;
        default: W = Wf; b = bf; out = h0; break;
    }
    const int row0 = blockIdx.x * 64;
    const int tid  = threadIdx.x;

    // stage 64x128 feats tile (float4, coalesced), clamp OOB rows to 0
    #pragma unroll
    for (int i = 0; i < 8; ++i) {
        int idx = tid + i * 256;          // float4 index within tile
        int r   = idx >> 5;
        int c4  = idx & 31;
        int gr  = row0 + r;
        const float4* src =
            reinterpret_cast<const float4*>(feats + (size_t)(gr < N_NODES ? gr : 0) * FEATS) + c4;
        *reinterpret_cast<float4*>(&As[r][c4 * 4]) = *src;
    }
    __syncthreads();

    const int rg = tid >> 4;   // 0..15 -> rows rg*4..rg*4+3
    const int cg = tid & 15;   // 0..15 -> cols cg*8..cg*8+7
    float acc[4][8] = {};

    for (int kk = 0; kk < 128; ++kk) {
        float4 w0 = *reinterpret_cast<const float4*>(W + kk * 128 + cg * 8);
        float4 w1 = *reinterpret_cast<const float4*>(W + kk * 128 + cg * 8 + 4);
        float a[4];
        #pragma unroll
        for (int i = 0; i < 4; ++i) a[i] = As[rg * 4 + i][kk];
        #pragma unroll
        for (int i = 0; i < 4; ++i) {
            acc[i][0] += a[i] * w0.x; acc[i][1] += a[i] * w0.y;
            acc[i][2] += a[i] * w0.z; acc[i][3] += a[i] * w0.w;
            acc[i][4] += a[i] * w1.x; acc[i][5] += a[i] * w1.y;
            acc[i][6] += a[i] * w1.z; acc[i][7] += a[i] * w1.w;
        }
    }

    float4 b0 = *reinterpret_cast<const float4*>(b + cg * 8);
    float4 b1 = *reinterpret_cast<const float4*>(b + cg * 8 + 4);
    #pragma unroll
    for (int i = 0; i < 4; ++i) {
        int gr = row0 + rg * 4 + i;
        if (gr >= N_NODES) continue;
        float4 o0, o1;
        o0.x = acc[i][0] + b0.x; o0.y = acc[i][1] + b0.y;
        o0.z = acc[i][2] + b0.z; o0.w = acc[i][3] + b0.w;
        o1.x = acc[i][4] + b1.x; o1.y = acc[i][5] + b1.y;
        o1.z = acc[i][6] + b1.z; o1.w = acc[i][7] + b1.w;
        *reinterpret_cast<float4*>(out + (size_t)gr * 128 + cg * 8)     = o0;
        *reinterpret_cast<float4*>(out + (size_t)gr * 128 + cg * 8 + 4) = o1;
    }
}

// ---------------- Kernel 2: bucket build (reverse CSR, capacity 64) -------
__global__ __launch_bounds__(256) void bucket_kernel(
    const int* __restrict__ edst, int* __restrict__ cnt, int* __restrict__ bucket)
{
    int e = blockIdx.x * 256 + threadIdx.x;
    if (e >= N_EDGES) return;
    int d = edst[e];
    int pos = atomicAdd(&cnt[d], 1);
    if (pos < CAP) bucket[d * CAP + pos] = e;
}

// ---------------- Kernel 3: edge scores -----------------------------------
__global__ __launch_bounds__(256) void score_kernel(
    const float* __restrict__ q, const float* __restrict__ k,
    const int* __restrict__ esrc, const int* __restrict__ edst,
    float* __restrict__ score)
{
    int idx = blockIdx.x * 256 + threadIdx.x;   // e*8 + h
    if (idx >= N_EDGES * 8) return;
    int e = idx >> 3, h = idx & 7;
    int s = esrc[e], d = edst[e];
    const float4* kp = reinterpret_cast<const float4*>(k + (size_t)s * 128 + h * 16);
    const float4* qp = reinterpret_cast<const float4*>(q + (size_t)d * 128 + h * 16);
    float acc = 0.f;
    #pragma unroll
    for (int i = 0; i < 4; ++i) {
        float4 a = kp[i], b = qp[i];
        acc += a.x * b.x + a.y * b.y + a.z * b.z + a.w * b.w;
    }
    acc *= 0.08838834764831845f;              // 1/sqrt(128)
    acc = fminf(fmaxf(acc, -5.f), 5.f);
    score[idx] = __expf(acc);
}

// ---------------- Kernel 4: per-node aggregate (wave per node) ------------
__global__ __launch_bounds__(256) void agg_kernel(
    const float* __restrict__ v, const float* __restrict__ score,
    const int* __restrict__ esrc, const int* __restrict__ cnt,
    const int* __restrict__ bucket, float* __restrict__ wv)
{
    int wid  = threadIdx.x >> 6;
    int lane = threadIdx.x & 63;
    int node = blockIdx.x * 4 + wid;
    int deg  = cnt[node]; if (deg > CAP) deg = CAP;
    int h0   = lane >> 4;                       // head for dim "lane" (0..3)
    float acc0 = 0.f, acc1 = 0.f, z0 = 0.f, z1 = 0.f;
    const int* bk = bucket + (size_t)node * CAP;
    for (int i = 0; i < deg; ++i) {
        int e = bk[i];
        int s = esrc[e];
        float s0 = score[(size_t)e * 8 + h0];
        float s1 = score[(size_t)e * 8 + 4 + h0];
        float v0 = v[(size_t)s * 128 + lane];
        float v1 = v[(size_t)s * 128 + 64 + lane];
        acc0 += v0 * s0; acc1 += v1 * s1;
        z0 += s0; z1 += s1;
    }
    wv[(size_t)node * 128 + lane]      = acc0 / z0;
    wv[(size_t)node * 128 + 64 + lane] = acc1 / z1;
}

// ---------------- Kernel 5: o = wv@Wo + bo; h = h0 + o; out = h + LN(h) ---
__global__ __launch_bounds__(256) void out_kernel(
    const float* __restrict__ wv, const float* __restrict__ Wo,
    const float* __restrict__ bo, const float* __restrict__ ln_g,
    const float* __restrict__ ln_b, float* __restrict__ out)
{
    __shared__ float As[32][132];
    __shared__ float Hs[32][132];
    const int row0 = blockIdx.x * 32;
    const int tid  = threadIdx.x;

    #pragma unroll
    for (int i = 0; i < 4; ++i) {
        int idx = tid + i * 256;
        int r = idx >> 5, c4 = idx & 31;
        *reinterpret_cast<float4*>(&As[r][c4 * 4]) =
            reinterpret_cast<const float4*>(wv + (size_t)(row0 + r) * 128)[c4];
    }
    __syncthreads();

    const int rg = tid >> 5;   // 0..7  -> rows rg*4..+3
    const int cg = tid & 31;   // 0..31 -> cols cg*4..+3
    float acc[4][4] = {};
    for (int kk = 0; kk < 128; ++kk) {
        float4 w = *reinterpret_cast<const float4*>(Wo + kk * 128 + cg * 4);
        float a[4];
        #pragma unroll
        for (int i = 0; i < 4; ++i) a[i] = As[rg * 4 + i][kk];
        #pragma unroll
        for (int i = 0; i < 4; ++i) {
            acc[i][0] += a[i] * w.x; acc[i][1] += a[i] * w.y;
            acc[i][2] += a[i] * w.z; acc[i][3] += a[i] * w.w;
        }
    }

    float4 bias = *reinterpret_cast<const float4*>(bo + cg * 4);
    #pragma unroll
    for (int i = 0; i < 4; ++i) {
        int gr = row0 + rg * 4 + i;
        float4 h0v = *reinterpret_cast<const float4*>(out + (size_t)gr * 128 + cg * 4);
        float hx = h0v.x + acc[i][0] + bias.x;
        float hy = h0v.y + acc[i][1] + bias.y;
        float hz = h0v.z + acc[i][2] + bias.z;
        float hw = h0v.w + acc[i][3] + bias.w;
        Hs[rg * 4 + i][cg * 4 + 0] = hx;
        Hs[rg * 4 + i][cg * 4 + 1] = hy;
        Hs[rg * 4 + i][cg * 4 + 2] = hz;
        Hs[rg * 4 + i][cg * 4 + 3] = hw;
    }
    __syncthreads();

    // LayerNorm: 8 threads per row, 16 elems each
    const int row = tid >> 3;
    const int sub = tid & 7;
    float sum = 0.f, sq = 0.f;
    #pragma unroll
    for (int j = 0; j < 16; ++j) {
        float x = Hs[row][sub * 16 + j];
        sum += x; sq += x * x;
    }
    #pragma unroll
    for (int off = 4; off >= 1; off >>= 1) {
        sum += __shfl_down(sum, off, 8);
        sq  += __shfl_down(sq,  off, 8);
    }
    sum = __shfl(sum, 0, 8);
    sq  = __shfl(sq,  0, 8);
    float mu   = sum * (1.f / 128.f);
    float var  = sq * (1.f / 128.f) - mu * mu;
    float rsig = rsqrtf(var + 1e-5f);

    #pragma unroll
    for (int j4 = 0; j4 < 4; ++j4) {
        int c = sub * 16 + j4 * 4;
        float4 x = *reinterpret_cast<const float4*>(&Hs[row][c]);
        float4 g = *reinterpret_cast<const float4*>(ln_g + c);
        float4 b = *reinterpret_cast<const float4*>(ln_b + c);
        float4 r;
        r.x = x.x + (x.x - mu) * rsig * g.x + b.x;
        r.y = x.y + (x.y - mu) * rsig * g.y + b.y;
        r.z = x.z + (x.z - mu) * rsig * g.z + b.z;
        r.w = x.w + (x.w - mu) * rsig * g.w + b.w;
        *reinterpret_cast<float4*>(out + (size_t)(row0 + row) * 128 + c) = r;
    }
}

// ---------------- launch ---------------------------------------------------
extern "C" void kernel_launch(void* const* d_in, const int* in_sizes, int n_in,
                              void* d_out, int out_size, void* d_ws, size_t ws_size,
                              hipStream_t stream) {
    const float* feats = (const float*)d_in[0];
    const int*   esrc  = (const int*)d_in[1];
    const int*   edst  = (const int*)d_in[2];
    const float* Wq = (const float*)d_in[3];  const float* bq = (const float*)d_in[4];
    const float* Wk = (const float*)d_in[5];  const float* bk = (const float*)d_in[6];
    const float* Wv = (const float*)d_in[7];  const float* bv = (const float*)d_in[8];
    const float* Wo = (const float*)d_in[9];  const float* bo = (const float*)d_in[10];
    const float* Wf = (const float*)d_in[11]; const float* bf = (const float*)d_in[12];
    const float* lg = (const float*)d_in[13]; const float* lb = (const float*)d_in[14];
    float* out = (float*)d_out;

    char* ws = (char*)d_ws;
    const size_t NF = (size_t)N_NODES * 128 * sizeof(float);   // 51.2 MB
    float* q     = (float*)(ws);
    float* k     = (float*)(ws + NF);
    float* v     = (float*)(ws + 2 * NF);
    float* wv    = (float*)(ws + 3 * NF);
    float* score = (float*)(ws + 4 * NF);                       // E*8 f32 = 25.6 MB
    int*   cnt   = (int*)  (ws + 4 * NF + (size_t)N_EDGES * 8 * sizeof(float));
    int*   bucket= (int*)  (ws + 4 * NF + (size_t)N_EDGES * 8 * sizeof(float)
                                 + (size_t)N_NODES * sizeof(int));

    hipMemsetAsync(cnt, 0, (size_t)N_NODES * sizeof(int), stream);

    // projections q,k,v,h0  (h0 -> d_out)
    dim3 pg((N_NODES + 63) / 64, 4);
    proj_kernel<<<pg, 256, 0, stream>>>(feats, Wq, bq, Wk, bk, Wv, bv, Wf, bf,
                                        q, k, v, out);
    // reverse-CSR buckets
    bucket_kernel<<<(N_EDGES + 255) / 256, 256, 0, stream>>>(edst, cnt, bucket);
    // edge scores
    score_kernel<<<(N_EDGES * 8) / 256, 256, 0, stream>>>(q, k, esrc, edst, score);
    // per-node aggregation
    agg_kernel<<<N_NODES / 4, 256, 0, stream>>>(v, score, esrc, cnt, bucket, wv);
    // output projection + residual + layernorm
    out_kernel<<<N_NODES / 32, 256, 0, stream>>>(wv, Wo, bo, lg, lb, out);
}

// Round 2
// 353.162 us; speedup vs baseline: 1.7482x; 1.7482x over previous
//
#include <hip/hip_runtime.h>
#include <hip/hip_bf16.h>

#define N_NODES 100000
#define N_EDGES 800000
#define CAP     64

typedef unsigned short u16;
typedef unsigned int   u32;
typedef __attribute__((ext_vector_type(8))) short bf16x8;
typedef __attribute__((ext_vector_type(4))) float f32x4;

__device__ inline u32 pack_bf2(float a, float b) {
    __hip_bfloat16 ha = __float2bfloat16(a), hb = __float2bfloat16(b);
    u16 ua, ub;
    __builtin_memcpy(&ua, &ha, 2);
    __builtin_memcpy(&ub, &hb, 2);
    return (u32)ua | ((u32)ub << 16);
}
__device__ inline u16 to_bf16(float a) {
    __hip_bfloat16 h = __float2bfloat16(a);
    u16 u; __builtin_memcpy(&u, &h, 2);
    return u;
}

// ---------------- Kernel 0: weight prep (transpose + bf16) ----------------
// WcatT[n][kk] = W*(kk, n&127), n: 0-127 Wq, 128-255 Wk, 256-383 Wv, 384-511 Wffn
// WoT[n][kk]   = Wo[kk][n]
__global__ __launch_bounds__(256) void prep_weights(
    const float* __restrict__ Wq, const float* __restrict__ Wk,
    const float* __restrict__ Wv, const float* __restrict__ Wf,
    const float* __restrict__ Wo, u16* __restrict__ WcatT, u16* __restrict__ WoT)
{
    int idx = blockIdx.x * 256 + threadIdx.x;
    if (idx < 512 * 128) {
        int n = idx >> 7, kk = idx & 127;
        const float* W = (n < 128) ? Wq : (n < 256) ? Wk : (n < 384) ? Wv : Wf;
        WcatT[idx] = to_bf16(W[kk * 128 + (n & 127)]);
    } else if (idx < 512 * 128 + 128 * 128) {
        int i2 = idx - 512 * 128;
        int n = i2 >> 7, kk = i2 & 127;
        WoT[i2] = to_bf16(Wo[kk * 128 + n]);
    }
}

// ---------------- Kernel 1: fused projections via MFMA --------------------
// [q|k|v|h0](N,128) = feats(N,128) @ [Wq|Wk|Wv|Wf] + bias
// block 512 thr (8 waves), tile 64 rows x 512 cols; wave owns 64x64.
__global__ __launch_bounds__(512) void proj_mfma(
    const float* __restrict__ feats, const u16* __restrict__ WT,
    const float* __restrict__ bq, const float* __restrict__ bk,
    const float* __restrict__ bv, const float* __restrict__ bf_,
    u16* __restrict__ q, u16* __restrict__ k, u16* __restrict__ v,
    float* __restrict__ h0)
{
    __shared__ __align__(16) u16 As[64][136];   // bf16, pad 8 -> 2-way-free banks
    const int tid  = threadIdx.x;
    const int row0 = blockIdx.x * 64;

    // stage + convert feats tile: 64 rows x 128 cols, 1024 8-elem tasks
    #pragma unroll
    for (int i = 0; i < 2; ++i) {
        int idx = tid + i * 512;
        int r = idx >> 4, c8 = (idx & 15) * 8;
        int gr = row0 + r;
        float4 f0, f1;
        if (gr < N_NODES) {
            const float4* p = reinterpret_cast<const float4*>(feats + (size_t)gr * 128 + c8);
            f0 = p[0]; f1 = p[1];
        } else {
            f0 = make_float4(0.f,0.f,0.f,0.f); f1 = f0;
        }
        u32 u0 = pack_bf2(f0.x, f0.y), u1 = pack_bf2(f0.z, f0.w);
        u32 u2 = pack_bf2(f1.x, f1.y), u3 = pack_bf2(f1.z, f1.w);
        uint4 pk; pk.x=u0; pk.y=u1; pk.z=u2; pk.w=u3;
        *reinterpret_cast<uint4*>(&As[r][c8]) = pk;
    }
    __syncthreads();

    const int wid = tid >> 6, l = tid & 63;
    const int q4 = l >> 4, c16 = l & 15;
    const int colg0 = wid * 64;

    f32x4 acc[4][4];
    #pragma unroll
    for (int a = 0; a < 4; ++a)
        #pragma unroll
        for (int b = 0; b < 4; ++b)
            acc[a][b] = (f32x4){0.f,0.f,0.f,0.f};

    #pragma unroll
    for (int ks = 0; ks < 4; ++ks) {
        const int k0 = ks * 32 + q4 * 8;
        bf16x8 afr[4], bfr[4];
        #pragma unroll
        for (int mt = 0; mt < 4; ++mt)
            afr[mt] = *reinterpret_cast<const bf16x8*>(&As[mt * 16 + c16][k0]);
        #pragma unroll
        for (int nt = 0; nt < 4; ++nt)
            bfr[nt] = *reinterpret_cast<const bf16x8*>(WT + (size_t)(colg0 + nt * 16 + c16) * 128 + k0);
        #pragma unroll
        for (int mt = 0; mt < 4; ++mt)
            #pragma unroll
            for (int nt = 0; nt < 4; ++nt)
                acc[mt][nt] = __builtin_amdgcn_mfma_f32_16x16x32_bf16(afr[mt], bfr[nt], acc[mt][nt], 0, 0, 0);
    }

    // epilogue: wid 0-1 -> q, 2-3 -> k, 4-5 -> v, 6-7 -> h0 (fp32)
    const float* bias_src = (wid < 2) ? bq : (wid < 4) ? bk : (wid < 6) ? bv : bf_;
    u16* outb = (wid < 2) ? q : (wid < 4) ? k : v;
    const int cbase = colg0 - (wid >> 1) * 128;   // col within target [0,128)

    #pragma unroll
    for (int nt = 0; nt < 4; ++nt) {
        const int col = cbase + nt * 16 + c16;
        const float bias = bias_src[col];
        #pragma unroll
        for (int mt = 0; mt < 4; ++mt) {
            #pragma unroll
            for (int j = 0; j < 4; ++j) {
                int gr = row0 + mt * 16 + q4 * 4 + j;
                if (gr >= N_NODES) continue;
                float val = acc[mt][nt][j] + bias;
                if (wid >= 6) h0[(size_t)gr * 128 + col] = val;
                else          outb[(size_t)gr * 128 + col] = to_bf16(val);
            }
        }
    }
}

// ---------------- Kernel 2: bucket build (reverse CSR, capacity 64) -------
__global__ __launch_bounds__(256) void bucket_kernel(
    const int* __restrict__ edst, int* __restrict__ cnt, int* __restrict__ bucket)
{
    int e = blockIdx.x * 256 + threadIdx.x;
    if (e >= N_EDGES) return;
    int d = edst[e];
    int pos = atomicAdd(&cnt[d], 1);
    if (pos < CAP) bucket[d * CAP + pos] = e;
}

// ---------------- Kernel 3: fused score + aggregate (wave per node) -------
// lane holds dims 2l,2l+1; head h = l>>3 (8 lanes per head)
__global__ __launch_bounds__(256) void agg_fused(
    const u16* __restrict__ q, const u16* __restrict__ k, const u16* __restrict__ v,
    const int* __restrict__ esrc, const int* __restrict__ cnt,
    const int* __restrict__ bucket, u16* __restrict__ wv)
{
    const int wid  = threadIdx.x >> 6;
    const int lane = threadIdx.x & 63;
    const int node = blockIdx.x * 4 + wid;
    int deg = cnt[node]; if (deg > CAP) deg = CAP;

    const u32 qp = *reinterpret_cast<const u32*>(q + (size_t)node * 128 + 2 * lane);
    const float scale = 0.08838834764831845f;   // 1/sqrt(128)
    float qf0 = __uint_as_float(qp << 16) * scale;
    float qf1 = __uint_as_float(qp & 0xffff0000u) * scale;

    float acc0 = 0.f, acc1 = 0.f, z = 0.f;
    const int* bk = bucket + (size_t)node * CAP;
    for (int i = 0; i < deg; ++i) {
        int e = bk[i];
        int s = esrc[e];
        u32 kp = *reinterpret_cast<const u32*>(k + (size_t)s * 128 + 2 * lane);
        u32 vp = *reinterpret_cast<const u32*>(v + (size_t)s * 128 + 2 * lane);
        float p = __uint_as_float(kp << 16) * qf0 +
                  __uint_as_float(kp & 0xffff0000u) * qf1;
        p += __shfl_xor(p, 1);
        p += __shfl_xor(p, 2);
        p += __shfl_xor(p, 4);
        p = fminf(fmaxf(p, -5.f), 5.f);
        float sc = __expf(p);
        acc0 += __uint_as_float(vp << 16) * sc;
        acc1 += __uint_as_float(vp & 0xffff0000u) * sc;
        z += sc;
    }
    float inv = 1.f / z;
    u32* wvp = reinterpret_cast<u32*>(wv + (size_t)node * 128);
    wvp[lane] = pack_bf2(acc0 * inv, acc1 * inv);
}

// ---------------- Kernel 4: o = wv@Wo + bo; h = h0 + o; out = h + LN(h) ---
// block 256 thr (4 waves), tile 64 rows x 128 cols; wave owns 64x32.
__global__ __launch_bounds__(256) void out_mfma(
    const u16* __restrict__ wv, const u16* __restrict__ WoT,
    const float* __restrict__ bo, const float* __restrict__ lg,
    const float* __restrict__ lb, float* __restrict__ out)
{
    __shared__ __align__(16) u16 As[64][136];
    __shared__ float Hs[64][132];
    const int tid  = threadIdx.x;
    const int row0 = blockIdx.x * 64;

    #pragma unroll
    for (int i = 0; i < 4; ++i) {
        int idx = tid + i * 256;
        int r = idx >> 4, c8 = (idx & 15) * 8;
        int gr = row0 + r; if (gr >= N_NODES) gr = N_NODES - 1;
        *reinterpret_cast<uint4*>(&As[r][c8]) =
            *reinterpret_cast<const uint4*>(wv + (size_t)gr * 128 + c8);
    }
    __syncthreads();

    const int wid = tid >> 6, l = tid & 63;
    const int q4 = l >> 4, c16 = l & 15;
    const int col0 = wid * 32;

    f32x4 acc[4][2];
    #pragma unroll
    for (int a = 0; a < 4; ++a) { acc[a][0] = (f32x4){0.f,0.f,0.f,0.f}; acc[a][1] = acc[a][0]; }

    #pragma unroll
    for (int ks = 0; ks < 4; ++ks) {
        const int k0 = ks * 32 + q4 * 8;
        bf16x8 afr[4], bfr[2];
        #pragma unroll
        for (int mt = 0; mt < 4; ++mt)
            afr[mt] = *reinterpret_cast<const bf16x8*>(&As[mt * 16 + c16][k0]);
        #pragma unroll
        for (int nt = 0; nt < 2; ++nt)
            bfr[nt] = *reinterpret_cast<const bf16x8*>(WoT + (size_t)(col0 + nt * 16 + c16) * 128 + k0);
        #pragma unroll
        for (int mt = 0; mt < 4; ++mt)
            #pragma unroll
            for (int nt = 0; nt < 2; ++nt)
                acc[mt][nt] = __builtin_amdgcn_mfma_f32_16x16x32_bf16(afr[mt], bfr[nt], acc[mt][nt], 0, 0, 0);
    }

    // h = h0 + o + bo  -> Hs
    #pragma unroll
    for (int nt = 0; nt < 2; ++nt) {
        const int col = col0 + nt * 16 + c16;
        const float bias = bo[col];
        #pragma unroll
        for (int mt = 0; mt < 4; ++mt) {
            #pragma unroll
            for (int j = 0; j < 4; ++j) {
                int r = mt * 16 + q4 * 4 + j;
                int gr = row0 + r;
                float h0v = (gr < N_NODES) ? out[(size_t)gr * 128 + col] : 0.f;
                Hs[r][col] = h0v + acc[mt][nt][j] + bias;
            }
        }
    }
    __syncthreads();

    // LayerNorm: 4 threads per row, interleaved float4s (conflict-light)
    const int r   = tid >> 2;
    const int sub = tid & 3;
    float sum = 0.f, sq = 0.f;
    #pragma unroll
    for (int jj = 0; jj < 8; ++jj) {
        float4 x = *reinterpret_cast<const float4*>(&Hs[r][(sub + jj * 4) * 4]);
        sum += x.x + x.y + x.z + x.w;
        sq  += x.x*x.x + x.y*x.y + x.z*x.z + x.w*x.w;
    }
    sum += __shfl_xor(sum, 1); sq += __shfl_xor(sq, 1);
    sum += __shfl_xor(sum, 2); sq += __shfl_xor(sq, 2);
    float mu   = sum * (1.f / 128.f);
    float var  = sq * (1.f / 128.f) - mu * mu;
    float rsig = rsqrtf(var + 1e-5f);

    int gr = row0 + r;
    if (gr < N_NODES) {
        #pragma unroll
        for (int jj = 0; jj < 8; ++jj) {
            int c = (sub + jj * 4) * 4;
            float4 x = *reinterpret_cast<const float4*>(&Hs[r][c]);
            float4 g = *reinterpret_cast<const float4*>(lg + c);
            float4 b = *reinterpret_cast<const float4*>(lb + c);
            float4 o;
            o.x = x.x + (x.x - mu) * rsig * g.x + b.x;
            o.y = x.y + (x.y - mu) * rsig * g.y + b.y;
            o.z = x.z + (x.z - mu) * rsig * g.z + b.z;
            o.w = x.w + (x.w - mu) * rsig * g.w + b.w;
            *reinterpret_cast<float4*>(out + (size_t)gr * 128 + c) = o;
        }
    }
}

// ---------------- launch ---------------------------------------------------
extern "C" void kernel_launch(void* const* d_in, const int* in_sizes, int n_in,
                              void* d_out, int out_size, void* d_ws, size_t ws_size,
                              hipStream_t stream) {
    const float* feats = (const float*)d_in[0];
    const int*   esrc  = (const int*)d_in[1];
    const int*   edst  = (const int*)d_in[2];
    const float* Wq = (const float*)d_in[3];  const float* bq = (const float*)d_in[4];
    const float* Wk = (const float*)d_in[5];  const float* bk = (const float*)d_in[6];
    const float* Wv = (const float*)d_in[7];  const float* bv = (const float*)d_in[8];
    const float* Wo = (const float*)d_in[9];  const float* bo = (const float*)d_in[10];
    const float* Wf = (const float*)d_in[11]; const float* bf = (const float*)d_in[12];
    const float* lg = (const float*)d_in[13]; const float* lb = (const float*)d_in[14];
    float* out = (float*)d_out;

    char* ws = (char*)d_ws;
    const size_t NB = (size_t)N_NODES * 128 * sizeof(u16);     // 25.6 MB
    u16* q     = (u16*)(ws);
    u16* k     = (u16*)(ws + NB);
    u16* v     = (u16*)(ws + 2 * NB);
    u16* wv    = (u16*)(ws + 3 * NB);
    u16* WcatT = (u16*)(ws + 4 * NB);
    u16* WoT   = (u16*)(ws + 4 * NB + 512 * 128 * sizeof(u16));
    int* cnt   = (int*)(ws + 4 * NB + (512 * 128 + 128 * 128) * sizeof(u16));
    int* bucket= (int*)(ws + 4 * NB + (512 * 128 + 128 * 128) * sizeof(u16)
                             + (size_t)N_NODES * sizeof(int));

    hipMemsetAsync(cnt, 0, (size_t)N_NODES * sizeof(int), stream);

    prep_weights<<<320, 256, 0, stream>>>(Wq, Wk, Wv, Wf, Wo, WcatT, WoT);
    proj_mfma<<<(N_NODES + 63) / 64, 512, 0, stream>>>(feats, WcatT, bq, bk, bv, bf,
                                                       q, k, v, out);
    bucket_kernel<<<(N_EDGES + 255) / 256, 256, 0, stream>>>(edst, cnt, bucket);
    agg_fused<<<N_NODES / 4, 256, 0, stream>>>(q, k, v, esrc, cnt, bucket, wv);
    out_mfma<<<(N_NODES + 63) / 64, 256, 0, stream>>>(wv, WoT, bo, lg, lb, out);
}

// Round 5
// 239.663 us; speedup vs baseline: 2.5761x; 1.4736x over previous
//
#include <hip/hip_runtime.h>
#include <hip/hip_bf16.h>

#define N_NODES 100000
#define N_EDGES 800000
#define CAP     64

typedef unsigned short u16;
typedef unsigned int   u32;
typedef __attribute__((ext_vector_type(8))) short bf16x8;
typedef __attribute__((ext_vector_type(4))) float f32x4;

__device__ inline u32 pack_bf2(float a, float b) {
    __hip_bfloat16 ha = __float2bfloat16(a), hb = __float2bfloat16(b);
    u16 ua, ub;
    __builtin_memcpy(&ua, &ha, 2);
    __builtin_memcpy(&ub, &hb, 2);
    return (u32)ua | ((u32)ub << 16);
}
__device__ inline u16 to_bf16(float a) {
    __hip_bfloat16 h = __float2bfloat16(a);
    u16 u; __builtin_memcpy(&u, &h, 2);
    return u;
}
__device__ inline void unpk(u32 w, float& a, float& b) {
    a = __uint_as_float(w << 16);
    b = __uint_as_float(w & 0xffff0000u);
}

// ---------------- Kernel 0: weight prep (transpose + bf16) ----------------
// WcatT[n][kk]: n 0-127 WqT, 128-255 WkT, 256-383 WvT, 384-511 WffnT
// WoT[n][kk] = Wo[kk][n]
__global__ __launch_bounds__(256) void prep_weights(
    const float* __restrict__ Wq, const float* __restrict__ Wk,
    const float* __restrict__ Wv, const float* __restrict__ Wf,
    const float* __restrict__ Wo, u16* __restrict__ WcatT, u16* __restrict__ WoT)
{
    int idx = blockIdx.x * 256 + threadIdx.x;
    if (idx < 512 * 128) {
        int n = idx >> 7, kk = idx & 127;
        const float* W = (n < 128) ? Wq : (n < 256) ? Wk : (n < 384) ? Wv : Wf;
        WcatT[idx] = to_bf16(W[kk * 128 + (n & 127)]);
    } else if (idx < 512 * 128 + 128 * 128) {
        int i2 = idx - 512 * 128;
        int n = i2 >> 7, kk = i2 & 127;
        WoT[i2] = to_bf16(Wo[kk * 128 + n]);
    }
}

// ---------------- Kernel 1: q/k/v projections via MFMA --------------------
// block 384 thr (6 waves), tile 64 rows x 384 cols; wave owns 64x64.
__global__ __launch_bounds__(384) void proj_mfma(
    const float* __restrict__ feats, const u16* __restrict__ WT,
    const float* __restrict__ bq, const float* __restrict__ bk,
    const float* __restrict__ bv,
    u16* __restrict__ q, u16* __restrict__ k, u16* __restrict__ v)
{
    __shared__ __align__(16) u16 As[64][136];
    const int tid  = threadIdx.x;
    const int row0 = blockIdx.x * 64;

    #pragma unroll
    for (int i = 0; i < 3; ++i) {
        int idx = tid + i * 384;
        if (idx < 1024) {
            int r = idx >> 4, c8 = (idx & 15) * 8;
            int gr = row0 + r;
            float4 f0, f1;
            if (gr < N_NODES) {
                const float4* p = reinterpret_cast<const float4*>(feats + (size_t)gr * 128 + c8);
                f0 = p[0]; f1 = p[1];
            } else {
                f0 = make_float4(0.f,0.f,0.f,0.f); f1 = f0;
            }
            uint4 pk;
            pk.x = pack_bf2(f0.x, f0.y); pk.y = pack_bf2(f0.z, f0.w);
            pk.z = pack_bf2(f1.x, f1.y); pk.w = pack_bf2(f1.z, f1.w);
            *reinterpret_cast<uint4*>(&As[r][c8]) = pk;
        }
    }
    __syncthreads();

    const int wid = tid >> 6, l = tid & 63;
    const int q4 = l >> 4, c16 = l & 15;
    const int colg0 = wid * 64;

    f32x4 acc[4][4];
    #pragma unroll
    for (int a = 0; a < 4; ++a)
        #pragma unroll
        for (int b = 0; b < 4; ++b)
            acc[a][b] = (f32x4){0.f,0.f,0.f,0.f};

    #pragma unroll
    for (int ks = 0; ks < 4; ++ks) {
        const int k0 = ks * 32 + q4 * 8;
        bf16x8 afr[4], bfr[4];
        #pragma unroll
        for (int mt = 0; mt < 4; ++mt)
            afr[mt] = *reinterpret_cast<const bf16x8*>(&As[mt * 16 + c16][k0]);
        #pragma unroll
        for (int nt = 0; nt < 4; ++nt)
            bfr[nt] = *reinterpret_cast<const bf16x8*>(WT + (size_t)(colg0 + nt * 16 + c16) * 128 + k0);
        #pragma unroll
        for (int mt = 0; mt < 4; ++mt)
            #pragma unroll
            for (int nt = 0; nt < 4; ++nt)
                acc[mt][nt] = __builtin_amdgcn_mfma_f32_16x16x32_bf16(afr[mt], bfr[nt], acc[mt][nt], 0, 0, 0);
    }

    const float* bias_src = (wid < 2) ? bq : (wid < 4) ? bk : bv;
    u16* outb = (wid < 2) ? q : (wid < 4) ? k : v;
    const int cbase = colg0 - (wid >> 1) * 128;

    #pragma unroll
    for (int nt = 0; nt < 4; ++nt) {
        const int col = cbase + nt * 16 + c16;
        const float bias = bias_src[col];
        #pragma unroll
        for (int mt = 0; mt < 4; ++mt) {
            #pragma unroll
            for (int j = 0; j < 4; ++j) {
                int gr = row0 + mt * 16 + q4 * 4 + j;
                if (gr >= N_NODES) continue;
                outb[(size_t)gr * 128 + col] = to_bf16(acc[mt][nt][j] + bias);
            }
        }
    }
}

// ---------------- Kernel 2: bucket build (stores SRC id, not edge id) -----
__global__ __launch_bounds__(256) void bucket_kernel(
    const int* __restrict__ esrc, const int* __restrict__ edst,
    int* __restrict__ cnt, int* __restrict__ bucket)
{
    int e = blockIdx.x * 256 + threadIdx.x;
    if (e >= N_EDGES) return;
    int d = edst[e];
    int pos = atomicAdd(&cnt[d], 1);
    if (pos < CAP) bucket[(size_t)d * CAP + pos] = esrc[e];
}

// ---------------- Kernel 3: fused score + aggregate -----------------------
// wave per node; 8-lane group per edge (8 edges in flight); lane = head.
__global__ __launch_bounds__(256) void agg_fused(
    const u16* __restrict__ q, const u16* __restrict__ k, const u16* __restrict__ v,
    const int* __restrict__ cnt, const int* __restrict__ bucket,
    u16* __restrict__ wv)
{
    const int wid  = threadIdx.x >> 6;
    const int lane = threadIdx.x & 63;
    const int node = blockIdx.x * 4 + wid;
    int deg = cnt[node]; if (deg > CAP) deg = CAP;

    const int grp = lane >> 3;   // edge slot within iteration (0..7)
    const int el  = lane & 7;    // head index

    // q fragment for this lane's head, prescaled by 1/sqrt(128)
    const float scale = 0.08838834764831845f;
    const uint4* qp = reinterpret_cast<const uint4*>(q + (size_t)node * 128 + el * 16);
    uint4 q0 = qp[0], q1 = qp[1];
    float qf[16];
    {
        u32 qw[8] = {q0.x,q0.y,q0.z,q0.w,q1.x,q1.y,q1.z,q1.w};
        #pragma unroll
        for (int j = 0; j < 8; ++j) {
            float a, b; unpk(qw[j], a, b);
            qf[2*j] = a * scale; qf[2*j+1] = b * scale;
        }
    }

    // preload all src ids: lane i holds bucket[node][i]
    int srcs = (lane < deg) ? bucket[(size_t)node * CAP + lane] : 0;

    float acc[16];
    #pragma unroll
    for (int j = 0; j < 16; ++j) acc[j] = 0.f;
    float z = 0.f;

    const int nIter = (deg + 7) >> 3;
    for (int it = 0; it < nIter; ++it) {
        int i = it * 8 + grp;
        bool valid = (i < deg);
        int s = __shfl(srcs, i);
        const uint4* kp = reinterpret_cast<const uint4*>(k + (size_t)s * 128 + el * 16);
        uint4 k0 = kp[0], k1 = kp[1];
        const uint4* vp = reinterpret_cast<const uint4*>(v + (size_t)s * 128 + el * 16);
        uint4 v0 = vp[0], v1 = vp[1];

        u32 kw[8] = {k0.x,k0.y,k0.z,k0.w,k1.x,k1.y,k1.z,k1.w};
        float p = 0.f;
        #pragma unroll
        for (int j = 0; j < 8; ++j) {
            float a, b; unpk(kw[j], a, b);
            p = fmaf(a, qf[2*j], p);
            p = fmaf(b, qf[2*j+1], p);
        }
        p = fminf(fmaxf(p, -5.f), 5.f);
        float sc = valid ? __expf(p) : 0.f;

        u32 vw[8] = {v0.x,v0.y,v0.z,v0.w,v1.x,v1.y,v1.z,v1.w};
        #pragma unroll
        for (int j = 0; j < 8; ++j) {
            float a, b; unpk(vw[j], a, b);
            acc[2*j]   = fmaf(a, sc, acc[2*j]);
            acc[2*j+1] = fmaf(b, sc, acc[2*j+1]);
        }
        z += sc;
    }

    // reduce across the 8 edge-groups (lanes with equal el)
    #pragma unroll
    for (int mask = 8; mask <= 32; mask <<= 1) {
        #pragma unroll
        for (int j = 0; j < 16; ++j) acc[j] += __shfl_xor(acc[j], mask);
        z += __shfl_xor(z, mask);
    }

    if (grp == 0) {   // lanes 0..7: head el writes dims el*16..el*16+15
        float inv = 1.f / z;
        uint4 w0, w1;
        w0.x = pack_bf2(acc[0]*inv,  acc[1]*inv);
        w0.y = pack_bf2(acc[2]*inv,  acc[3]*inv);
        w0.z = pack_bf2(acc[4]*inv,  acc[5]*inv);
        w0.w = pack_bf2(acc[6]*inv,  acc[7]*inv);
        w1.x = pack_bf2(acc[8]*inv,  acc[9]*inv);
        w1.y = pack_bf2(acc[10]*inv, acc[11]*inv);
        w1.z = pack_bf2(acc[12]*inv, acc[13]*inv);
        w1.w = pack_bf2(acc[14]*inv, acc[15]*inv);
        uint4* wp = reinterpret_cast<uint4*>(wv + (size_t)node * 128 + el * 16);
        wp[0] = w0; wp[1] = w1;
    }
}

// ---------------- Kernel 4: h0 = feats@Wffn; o = wv@Wo; h = h0+o+biases; --
//                  out = h + LN(h). block 256 thr, tile 64 rows.
__global__ __launch_bounds__(256) void out_mfma(
    const float* __restrict__ feats, const u16* __restrict__ wv,
    const u16* __restrict__ WoT, const u16* __restrict__ WcatT,
    const float* __restrict__ bo, const float* __restrict__ bffn,
    const float* __restrict__ lg, const float* __restrict__ lb,
    float* __restrict__ out)
{
    __shared__ __align__(16) char smem[2 * 64 * 136 * sizeof(u16)];
    u16 (*Awv)[136] = reinterpret_cast<u16(*)[136]>(smem);
    u16 (*Aft)[136] = reinterpret_cast<u16(*)[136]>(smem + 64 * 136 * sizeof(u16));
    float (*Hs)[132] = reinterpret_cast<float(*)[132]>(smem);   // reused later

    const int tid  = threadIdx.x;
    const int row0 = blockIdx.x * 64;
    const u16* WfT = WcatT + 384 * 128;

    // stage wv (bf16 copy) and feats (fp32 -> bf16)
    #pragma unroll
    for (int i = 0; i < 4; ++i) {
        int idx = tid + i * 256;
        int r = idx >> 4, c8 = (idx & 15) * 8;
        int gr = row0 + r; if (gr >= N_NODES) gr = N_NODES - 1;
        *reinterpret_cast<uint4*>(&Awv[r][c8]) =
            *reinterpret_cast<const uint4*>(wv + (size_t)gr * 128 + c8);
        const float4* p = reinterpret_cast<const float4*>(feats + (size_t)gr * 128 + c8);
        float4 f0 = p[0], f1 = p[1];
        uint4 pk;
        pk.x = pack_bf2(f0.x, f0.y); pk.y = pack_bf2(f0.z, f0.w);
        pk.z = pack_bf2(f1.x, f1.y); pk.w = pack_bf2(f1.z, f1.w);
        *reinterpret_cast<uint4*>(&Aft[r][c8]) = pk;
    }
    __syncthreads();

    const int wid = tid >> 6, l = tid & 63;
    const int q4 = l >> 4, c16 = l & 15;
    const int col0 = wid * 32;

    f32x4 acc[4][2];
    #pragma unroll
    for (int a = 0; a < 4; ++a) { acc[a][0] = (f32x4){0.f,0.f,0.f,0.f}; acc[a][1] = acc[a][0]; }

    #pragma unroll
    for (int ks = 0; ks < 4; ++ks) {
        const int k0 = ks * 32 + q4 * 8;
        bf16x8 afr[4], bfr[2];
        #pragma unroll
        for (int mt = 0; mt < 4; ++mt)
            afr[mt] = *reinterpret_cast<const bf16x8*>(&Awv[mt * 16 + c16][k0]);
        #pragma unroll
        for (int nt = 0; nt < 2; ++nt)
            bfr[nt] = *reinterpret_cast<const bf16x8*>(WoT + (size_t)(col0 + nt * 16 + c16) * 128 + k0);
        #pragma unroll
        for (int mt = 0; mt < 4; ++mt)
            #pragma unroll
            for (int nt = 0; nt < 2; ++nt)
                acc[mt][nt] = __builtin_amdgcn_mfma_f32_16x16x32_bf16(afr[mt], bfr[nt], acc[mt][nt], 0, 0, 0);
    }
    #pragma unroll
    for (int ks = 0; ks < 4; ++ks) {
        const int k0 = ks * 32 + q4 * 8;
        bf16x8 afr[4], bfr[2];
        #pragma unroll
        for (int mt = 0; mt < 4; ++mt)
            afr[mt] = *reinterpret_cast<const bf16x8*>(&Aft[mt * 16 + c16][k0]);
        #pragma unroll
        for (int nt = 0; nt < 2; ++nt)
            bfr[nt] = *reinterpret_cast<const bf16x8*>(WfT + (size_t)(col0 + nt * 16 + c16) * 128 + k0);
        #pragma unroll
        for (int mt = 0; mt < 4; ++mt)
            #pragma unroll
            for (int nt = 0; nt < 2; ++nt)
                acc[mt][nt] = __builtin_amdgcn_mfma_f32_16x16x32_bf16(afr[mt], bfr[nt], acc[mt][nt], 0, 0, 0);
    }
    __syncthreads();    // done reading Awv/Aft; smem becomes Hs

    #pragma unroll
    for (int nt = 0; nt < 2; ++nt) {
        const int col = col0 + nt * 16 + c16;
        const float bias = bo[col] + bffn[col];
        #pragma unroll
        for (int mt = 0; mt < 4; ++mt) {
            #pragma unroll
            for (int j = 0; j < 4; ++j) {
                int r = mt * 16 + q4 * 4 + j;
                Hs[r][col] = acc[mt][nt][j] + bias;
            }
        }
    }
    __syncthreads();

    // LayerNorm: 4 threads per row
    const int r   = tid >> 2;
    const int sub = tid & 3;
    float sum = 0.f, sq = 0.f;
    #pragma unroll
    for (int jj = 0; jj < 8; ++jj) {
        float4 x = *reinterpret_cast<const float4*>(&Hs[r][(sub + jj * 4) * 4]);
        sum += x.x + x.y + x.z + x.w;
        sq  += x.x*x.x + x.y*x.y + x.z*x.z + x.w*x.w;
    }
    sum += __shfl_xor(sum, 1); sq += __shfl_xor(sq, 1);
    sum += __shfl_xor(sum, 2); sq += __shfl_xor(sq, 2);
    float mu   = sum * (1.f / 128.f);
    float var  = sq * (1.f / 128.f) - mu * mu;
    float rsig = rsqrtf(var + 1e-5f);

    int gr = row0 + r;
    if (gr < N_NODES) {
        #pragma unroll
        for (int jj = 0; jj < 8; ++jj) {
            int c = (sub + jj * 4) * 4;
            float4 x = *reinterpret_cast<const float4*>(&Hs[r][c]);
            float4 g = *reinterpret_cast<const float4*>(lg + c);
            float4 b = *reinterpret_cast<const float4*>(lb + c);
            float4 o;
            o.x = x.x + (x.x - mu) * rsig * g.x + b.x;
            o.y = x.y + (x.y - mu) * rsig * g.y + b.y;
            o.z = x.z + (x.z - mu) * rsig * g.z + b.z;
            o.w = x.w + (x.w - mu) * rsig * g.w + b.w;
            *reinterpret_cast<float4*>(out + (size_t)gr * 128 + c) = o;
        }
    }
}

// ---------------- launch ---------------------------------------------------
extern "C" void kernel_launch(void* const* d_in, const int* in_sizes, int n_in,
                              void* d_out, int out_size, void* d_ws, size_t ws_size,
                              hipStream_t stream) {
    const float* feats = (const float*)d_in[0];
    const int*   esrc  = (const int*)d_in[1];
    const int*   edst  = (const int*)d_in[2];
    const float* Wq = (const float*)d_in[3];  const float* bq = (const float*)d_in[4];
    const float* Wk = (const float*)d_in[5];  const float* bk = (const float*)d_in[6];
    const float* Wv = (const float*)d_in[7];  const float* bv = (const float*)d_in[8];
    const float* Wo = (const float*)d_in[9];  const float* bo = (const float*)d_in[10];
    const float* Wf = (const float*)d_in[11]; const float* bf = (const float*)d_in[12];
    const float* lg = (const float*)d_in[13]; const float* lb = (const float*)d_in[14];
    float* out = (float*)d_out;

    char* ws = (char*)d_ws;
    const size_t NB = (size_t)N_NODES * 128 * sizeof(u16);     // 25.6 MB
    u16* q     = (u16*)(ws);
    u16* k     = (u16*)(ws + NB);
    u16* v     = (u16*)(ws + 2 * NB);
    u16* wv    = (u16*)(ws + 3 * NB);
    u16* WcatT = (u16*)(ws + 4 * NB);
    u16* WoT   = (u16*)(ws + 4 * NB + 512 * 128 * sizeof(u16));
    int* cnt   = (int*)(ws + 4 * NB + (512 * 128 + 128 * 128) * sizeof(u16));
    int* bucket= (int*)(ws + 4 * NB + (512 * 128 + 128 * 128) * sizeof(u16)
                             + (size_t)N_NODES * sizeof(int));

    hipMemsetAsync(cnt, 0, (size_t)N_NODES * sizeof(int), stream);

    prep_weights<<<320, 256, 0, stream>>>(Wq, Wk, Wv, Wf, Wo, WcatT, WoT);
    proj_mfma<<<(N_NODES + 63) / 64, 384, 0, stream>>>(feats, WcatT, bq, bk, bv,
                                                       q, k, v);
    bucket_kernel<<<(N_EDGES + 255) / 256, 256, 0, stream>>>(esrc, edst, cnt, bucket);
    agg_fused<<<N_NODES / 4, 256, 0, stream>>>(q, k, v, cnt, bucket, wv);
    out_mfma<<<(N_NODES + 63) / 64, 256, 0, stream>>>(feats, wv, WoT, WcatT,
                                                      bo, bf, lg, lb, out);
}

// Round 6
// 219.964 us; speedup vs baseline: 2.8068x; 1.0896x over previous
//
#include <hip/hip_runtime.h>
#include <hip/hip_bf16.h>

#define N_NODES 100000
#define N_EDGES 800000
#define CAP     64
#define NTILES  ((N_NODES + 63) / 64)   // 1563

typedef unsigned short u16;
typedef unsigned int   u32;
typedef __attribute__((ext_vector_type(8))) short bf16x8;
typedef __attribute__((ext_vector_type(4))) float f32x4;

__device__ inline u32 pack_bf2(float a, float b) {
    __hip_bfloat16 ha = __float2bfloat16(a), hb = __float2bfloat16(b);
    u16 ua, ub;
    __builtin_memcpy(&ua, &ha, 2);
    __builtin_memcpy(&ub, &hb, 2);
    return (u32)ua | ((u32)ub << 16);
}
__device__ inline u16 to_bf16(float a) {
    __hip_bfloat16 h = __float2bfloat16(a);
    u16 u; __builtin_memcpy(&u, &h, 2);
    return u;
}
__device__ inline void unpk(u32 w, float& a, float& b) {
    a = __uint_as_float(w << 16);
    b = __uint_as_float(w & 0xffff0000u);
}

// ---------------- Kernel 0: weight prep (transpose + bf16) ----------------
// WcatT[n][kk]: n 0-127 WqT, 128-255 WkT, 256-383 WvT, 384-511 WffnT
// WoT[n][kk] = Wo[kk][n]
__global__ __launch_bounds__(256) void prep_weights(
    const float* __restrict__ Wq, const float* __restrict__ Wk,
    const float* __restrict__ Wv, const float* __restrict__ Wf,
    const float* __restrict__ Wo, u16* __restrict__ WcatT, u16* __restrict__ WoT)
{
    int idx = blockIdx.x * 256 + threadIdx.x;
    if (idx < 512 * 128) {
        int n = idx >> 7, kk = idx & 127;
        const float* W = (n < 128) ? Wq : (n < 256) ? Wk : (n < 384) ? Wv : Wf;
        WcatT[idx] = to_bf16(W[kk * 128 + (n & 127)]);
    } else if (idx < 512 * 128 + 128 * 128) {
        int i2 = idx - 512 * 128;
        int n = i2 >> 7, kk = i2 & 127;
        WoT[i2] = to_bf16(Wo[kk * 128 + n]);
    }
}

// ---------------- Kernel 1: q/k/v projections via MFMA --------------------
// 521 blocks x 384 thr (6 waves); grid-stride over 64-row tiles (3 each).
// Wave owns 64 rows x 64 cols. W frags cached in VGPRs. Swapped-operand
// MFMA (computes C^T fragment-wise) so each lane holds 4 consecutive output
// cols -> packed 8B stores.
__global__ __launch_bounds__(384, 3) void proj_mfma(
    const float* __restrict__ feats, const u16* __restrict__ WT,
    const float* __restrict__ bq, const float* __restrict__ bk,
    const float* __restrict__ bv,
    u16* __restrict__ q, u16* __restrict__ k, u16* __restrict__ v)
{
    __shared__ __align__(16) u16 As[64][136];
    const int tid = threadIdx.x;
    const int wid = tid >> 6, l = tid & 63;
    const int q4 = l >> 4, c16 = l & 15;
    const int colg0 = wid * 64;

    // cache weight fragments: wfr[ks][nt] = WT[col=colg0+nt*16+c16][ks*32+q4*8 ..+7]
    bf16x8 wfr[4][4];
    #pragma unroll
    for (int ks = 0; ks < 4; ++ks)
        #pragma unroll
        for (int nt = 0; nt < 4; ++nt)
            wfr[ks][nt] = *reinterpret_cast<const bf16x8*>(
                WT + (size_t)(colg0 + nt * 16 + c16) * 128 + ks * 32 + q4 * 8);

    const float* bias_src = (wid < 2) ? bq : (wid < 4) ? bk : bv;
    u16* outb = (wid < 2) ? q : (wid < 4) ? k : v;
    const int cbase = colg0 - (wid >> 1) * 128;    // col within target [0,128)

    for (int tile = blockIdx.x; tile < NTILES; tile += gridDim.x) {
        const int row0 = tile * 64;

        // stage + convert feats tile: 64 rows x 128 cols (1024 8-elem tasks)
        #pragma unroll
        for (int i = 0; i < 3; ++i) {
            int idx = tid + i * 384;
            if (idx < 1024) {
                int r = idx >> 4, c8 = (idx & 15) * 8;
                int gr = row0 + r;
                float4 f0, f1;
                if (gr < N_NODES) {
                    const float4* p = reinterpret_cast<const float4*>(feats + (size_t)gr * 128 + c8);
                    f0 = p[0]; f1 = p[1];
                } else {
                    f0 = make_float4(0.f,0.f,0.f,0.f); f1 = f0;
                }
                uint4 pk;
                pk.x = pack_bf2(f0.x, f0.y); pk.y = pack_bf2(f0.z, f0.w);
                pk.z = pack_bf2(f1.x, f1.y); pk.w = pack_bf2(f1.z, f1.w);
                *reinterpret_cast<uint4*>(&As[r][c8]) = pk;
            }
        }
        __syncthreads();

        f32x4 acc[4][4];    // [mt = 16-row group][nt = 16-col group]
        #pragma unroll
        for (int a = 0; a < 4; ++a)
            #pragma unroll
            for (int b = 0; b < 4; ++b)
                acc[a][b] = (f32x4){0.f,0.f,0.f,0.f};

        #pragma unroll
        for (int ks = 0; ks < 4; ++ks) {
            const int k0 = ks * 32 + q4 * 8;
            bf16x8 afr[4];
            #pragma unroll
            for (int mt = 0; mt < 4; ++mt)
                afr[mt] = *reinterpret_cast<const bf16x8*>(&As[mt * 16 + c16][k0]);
            // swapped operands: D^T fragment -> lane l, reg j =
            //   C[row = mt*16 + (l&15)][col = nt*16 + (l>>4)*4 + j]
            #pragma unroll
            for (int mt = 0; mt < 4; ++mt)
                #pragma unroll
                for (int nt = 0; nt < 4; ++nt)
                    acc[mt][nt] = __builtin_amdgcn_mfma_f32_16x16x32_bf16(
                        wfr[ks][nt], afr[mt], acc[mt][nt], 0, 0, 0);
        }

        // packed 8B stores: 16 per thread (vs 64 scalar u16)
        #pragma unroll
        for (int nt = 0; nt < 4; ++nt) {
            const int c = cbase + nt * 16 + q4 * 4;
            float4 b4 = *reinterpret_cast<const float4*>(bias_src + c);
            #pragma unroll
            for (int mt = 0; mt < 4; ++mt) {
                int gr = row0 + mt * 16 + c16;
                if (gr < N_NODES) {
                    uint2 pk;
                    pk.x = pack_bf2(acc[mt][nt][0] + b4.x, acc[mt][nt][1] + b4.y);
                    pk.y = pack_bf2(acc[mt][nt][2] + b4.z, acc[mt][nt][3] + b4.w);
                    *reinterpret_cast<uint2*>(outb + (size_t)gr * 128 + c) = pk;
                }
            }
        }
        __syncthreads();
    }
}

// ---------------- Kernel 2: bucket build (stores SRC id, not edge id) -----
__global__ __launch_bounds__(256) void bucket_kernel(
    const int* __restrict__ esrc, const int* __restrict__ edst,
    int* __restrict__ cnt, int* __restrict__ bucket)
{
    int e = blockIdx.x * 256 + threadIdx.x;
    if (e >= N_EDGES) return;
    int d = edst[e];
    int pos = atomicAdd(&cnt[d], 1);
    if (pos < CAP) bucket[(size_t)d * CAP + pos] = esrc[e];
}

// ---------------- Kernel 3: fused score + aggregate -----------------------
// wave per node; 8-lane group per edge (8 edges in flight); lane = head.
__global__ __launch_bounds__(256) void agg_fused(
    const u16* __restrict__ q, const u16* __restrict__ k, const u16* __restrict__ v,
    const int* __restrict__ cnt, const int* __restrict__ bucket,
    u16* __restrict__ wv)
{
    const int wid  = threadIdx.x >> 6;
    const int lane = threadIdx.x & 63;
    const int node = blockIdx.x * 4 + wid;
    int deg = cnt[node]; if (deg > CAP) deg = CAP;

    const int grp = lane >> 3;   // edge slot within iteration (0..7)
    const int el  = lane & 7;    // head index

    // q fragment for this lane's head, prescaled by 1/sqrt(128)
    const float scale = 0.08838834764831845f;
    const uint4* qp = reinterpret_cast<const uint4*>(q + (size_t)node * 128 + el * 16);
    uint4 q0 = qp[0], q1 = qp[1];
    float qf[16];
    {
        u32 qw[8] = {q0.x,q0.y,q0.z,q0.w,q1.x,q1.y,q1.z,q1.w};
        #pragma unroll
        for (int j = 0; j < 8; ++j) {
            float a, b; unpk(qw[j], a, b);
            qf[2*j] = a * scale; qf[2*j+1] = b * scale;
        }
    }

    // preload all src ids: lane i holds bucket[node][i]
    int srcs = (lane < deg) ? bucket[(size_t)node * CAP + lane] : 0;

    float acc[16];
    #pragma unroll
    for (int j = 0; j < 16; ++j) acc[j] = 0.f;
    float z = 0.f;

    const int nIter = (deg + 7) >> 3;
    for (int it = 0; it < nIter; ++it) {
        int i = it * 8 + grp;
        bool valid = (i < deg);
        int s = __shfl(srcs, i);
        const uint4* kp = reinterpret_cast<const uint4*>(k + (size_t)s * 128 + el * 16);
        uint4 k0 = kp[0], k1 = kp[1];
        const uint4* vp = reinterpret_cast<const uint4*>(v + (size_t)s * 128 + el * 16);
        uint4 v0 = vp[0], v1 = vp[1];

        u32 kw[8] = {k0.x,k0.y,k0.z,k0.w,k1.x,k1.y,k1.z,k1.w};
        float p = 0.f;
        #pragma unroll
        for (int j = 0; j < 8; ++j) {
            float a, b; unpk(kw[j], a, b);
            p = fmaf(a, qf[2*j], p);
            p = fmaf(b, qf[2*j+1], p);
        }
        p = fminf(fmaxf(p, -5.f), 5.f);
        float sc = valid ? __expf(p) : 0.f;

        u32 vw[8] = {v0.x,v0.y,v0.z,v0.w,v1.x,v1.y,v1.z,v1.w};
        #pragma unroll
        for (int j = 0; j < 8; ++j) {
            float a, b; unpk(vw[j], a, b);
            acc[2*j]   = fmaf(a, sc, acc[2*j]);
            acc[2*j+1] = fmaf(b, sc, acc[2*j+1]);
        }
        z += sc;
    }

    // reduce across the 8 edge-groups (lanes with equal el)
    #pragma unroll
    for (int mask = 8; mask <= 32; mask <<= 1) {
        #pragma unroll
        for (int j = 0; j < 16; ++j) acc[j] += __shfl_xor(acc[j], mask);
        z += __shfl_xor(z, mask);
    }

    if (grp == 0) {   // lanes 0..7: head el writes dims el*16..el*16+15
        float inv = 1.f / z;
        uint4 w0, w1;
        w0.x = pack_bf2(acc[0]*inv,  acc[1]*inv);
        w0.y = pack_bf2(acc[2]*inv,  acc[3]*inv);
        w0.z = pack_bf2(acc[4]*inv,  acc[5]*inv);
        w0.w = pack_bf2(acc[6]*inv,  acc[7]*inv);
        w1.x = pack_bf2(acc[8]*inv,  acc[9]*inv);
        w1.y = pack_bf2(acc[10]*inv, acc[11]*inv);
        w1.z = pack_bf2(acc[12]*inv, acc[13]*inv);
        w1.w = pack_bf2(acc[14]*inv, acc[15]*inv);
        uint4* wp = reinterpret_cast<uint4*>(wv + (size_t)node * 128 + el * 16);
        wp[0] = w0; wp[1] = w1;
    }
}

// ---------------- Kernel 4: h0 = feats@Wffn; o = wv@Wo; h = h0+o+biases; --
//                  out = h + LN(h). block 256 thr, tile 64 rows.
__global__ __launch_bounds__(256) void out_mfma(
    const float* __restrict__ feats, const u16* __restrict__ wv,
    const u16* __restrict__ WoT, const u16* __restrict__ WcatT,
    const float* __restrict__ bo, const float* __restrict__ bffn,
    const float* __restrict__ lg, const float* __restrict__ lb,
    float* __restrict__ out)
{
    __shared__ __align__(16) char smem[2 * 64 * 136 * sizeof(u16)];
    u16 (*Awv)[136] = reinterpret_cast<u16(*)[136]>(smem);
    u16 (*Aft)[136] = reinterpret_cast<u16(*)[136]>(smem + 64 * 136 * sizeof(u16));
    float (*Hs)[132] = reinterpret_cast<float(*)[132]>(smem);   // reused later

    const int tid  = threadIdx.x;
    const int row0 = blockIdx.x * 64;
    const u16* WfT = WcatT + 384 * 128;

    // stage wv (bf16 copy) and feats (fp32 -> bf16)
    #pragma unroll
    for (int i = 0; i < 4; ++i) {
        int idx = tid + i * 256;
        int r = idx >> 4, c8 = (idx & 15) * 8;
        int gr = row0 + r; if (gr >= N_NODES) gr = N_NODES - 1;
        *reinterpret_cast<uint4*>(&Awv[r][c8]) =
            *reinterpret_cast<const uint4*>(wv + (size_t)gr * 128 + c8);
        const float4* p = reinterpret_cast<const float4*>(feats + (size_t)gr * 128 + c8);
        float4 f0 = p[0], f1 = p[1];
        uint4 pk;
        pk.x = pack_bf2(f0.x, f0.y); pk.y = pack_bf2(f0.z, f0.w);
        pk.z = pack_bf2(f1.x, f1.y); pk.w = pack_bf2(f1.z, f1.w);
        *reinterpret_cast<uint4*>(&Aft[r][c8]) = pk;
    }
    __syncthreads();

    const int wid = tid >> 6, l = tid & 63;
    const int q4 = l >> 4, c16 = l & 15;
    const int col0 = wid * 32;

    f32x4 acc[4][2];
    #pragma unroll
    for (int a = 0; a < 4; ++a) { acc[a][0] = (f32x4){0.f,0.f,0.f,0.f}; acc[a][1] = acc[a][0]; }

    #pragma unroll
    for (int ks = 0; ks < 4; ++ks) {
        const int k0 = ks * 32 + q4 * 8;
        bf16x8 afr[4], bfr[2];
        #pragma unroll
        for (int mt = 0; mt < 4; ++mt)
            afr[mt] = *reinterpret_cast<const bf16x8*>(&Awv[mt * 16 + c16][k0]);
        #pragma unroll
        for (int nt = 0; nt < 2; ++nt)
            bfr[nt] = *reinterpret_cast<const bf16x8*>(WoT + (size_t)(col0 + nt * 16 + c16) * 128 + k0);
        #pragma unroll
        for (int mt = 0; mt < 4; ++mt)
            #pragma unroll
            for (int nt = 0; nt < 2; ++nt)
                acc[mt][nt] = __builtin_amdgcn_mfma_f32_16x16x32_bf16(afr[mt], bfr[nt], acc[mt][nt], 0, 0, 0);
    }
    #pragma unroll
    for (int ks = 0; ks < 4; ++ks) {
        const int k0 = ks * 32 + q4 * 8;
        bf16x8 afr[4], bfr[2];
        #pragma unroll
        for (int mt = 0; mt < 4; ++mt)
            afr[mt] = *reinterpret_cast<const bf16x8*>(&Aft[mt * 16 + c16][k0]);
        #pragma unroll
        for (int nt = 0; nt < 2; ++nt)
            bfr[nt] = *reinterpret_cast<const bf16x8*>(WfT + (size_t)(col0 + nt * 16 + c16) * 128 + k0);
        #pragma unroll
        for (int mt = 0; mt < 4; ++mt)
            #pragma unroll
            for (int nt = 0; nt < 2; ++nt)
                acc[mt][nt] = __builtin_amdgcn_mfma_f32_16x16x32_bf16(afr[mt], bfr[nt], acc[mt][nt], 0, 0, 0);
    }
    __syncthreads();    // done reading Awv/Aft; smem becomes Hs

    #pragma unroll
    for (int nt = 0; nt < 2; ++nt) {
        const int col = col0 + nt * 16 + c16;
        const float bias = bo[col] + bffn[col];
        #pragma unroll
        for (int mt = 0; mt < 4; ++mt) {
            #pragma unroll
            for (int j = 0; j < 4; ++j) {
                int r = mt * 16 + q4 * 4 + j;
                Hs[r][col] = acc[mt][nt][j] + bias;
            }
        }
    }
    __syncthreads();

    // LayerNorm: 4 threads per row
    const int r   = tid >> 2;
    const int sub = tid & 3;
    float sum = 0.f, sq = 0.f;
    #pragma unroll
    for (int jj = 0; jj < 8; ++jj) {
        float4 x = *reinterpret_cast<const float4*>(&Hs[r][(sub + jj * 4) * 4]);
        sum += x.x + x.y + x.z + x.w;
        sq  += x.x*x.x + x.y*x.y + x.z*x.z + x.w*x.w;
    }
    sum += __shfl_xor(sum, 1); sq += __shfl_xor(sq, 1);
    sum += __shfl_xor(sum, 2); sq += __shfl_xor(sq, 2);
    float mu   = sum * (1.f / 128.f);
    float var  = sq * (1.f / 128.f) - mu * mu;
    float rsig = rsqrtf(var + 1e-5f);

    int gr = row0 + r;
    if (gr < N_NODES) {
        #pragma unroll
        for (int jj = 0; jj < 8; ++jj) {
            int c = (sub + jj * 4) * 4;
            float4 x = *reinterpret_cast<const float4*>(&Hs[r][c]);
            float4 g = *reinterpret_cast<const float4*>(lg + c);
            float4 b = *reinterpret_cast<const float4*>(lb + c);
            float4 o;
            o.x = x.x + (x.x - mu) * rsig * g.x + b.x;
            o.y = x.y + (x.y - mu) * rsig * g.y + b.y;
            o.z = x.z + (x.z - mu) * rsig * g.z + b.z;
            o.w = x.w + (x.w - mu) * rsig * g.w + b.w;
            *reinterpret_cast<float4*>(out + (size_t)gr * 128 + c) = o;
        }
    }
}

// ---------------- launch ---------------------------------------------------
extern "C" void kernel_launch(void* const* d_in, const int* in_sizes, int n_in,
                              void* d_out, int out_size, void* d_ws, size_t ws_size,
                              hipStream_t stream) {
    const float* feats = (const float*)d_in[0];
    const int*   esrc  = (const int*)d_in[1];
    const int*   edst  = (const int*)d_in[2];
    const float* Wq = (const float*)d_in[3];  const float* bq = (const float*)d_in[4];
    const float* Wk = (const float*)d_in[5];  const float* bk = (const float*)d_in[6];
    const float* Wv = (const float*)d_in[7];  const float* bv = (const float*)d_in[8];
    const float* Wo = (const float*)d_in[9];  const float* bo = (const float*)d_in[10];
    const float* Wf = (const float*)d_in[11]; const float* bf = (const float*)d_in[12];
    const float* lg = (const float*)d_in[13]; const float* lb = (const float*)d_in[14];
    float* out = (float*)d_out;

    char* ws = (char*)d_ws;
    const size_t NB = (size_t)N_NODES * 128 * sizeof(u16);     // 25.6 MB
    u16* q     = (u16*)(ws);
    u16* k     = (u16*)(ws + NB);
    u16* v     = (u16*)(ws + 2 * NB);
    u16* wv    = (u16*)(ws + 3 * NB);
    u16* WcatT = (u16*)(ws + 4 * NB);
    u16* WoT   = (u16*)(ws + 4 * NB + 512 * 128 * sizeof(u16));
    int* cnt   = (int*)(ws + 4 * NB + (512 * 128 + 128 * 128) * sizeof(u16));
    int* bucket= (int*)(ws + 4 * NB + (512 * 128 + 128 * 128) * sizeof(u16)
                             + (size_t)N_NODES * sizeof(int));

    hipMemsetAsync(cnt, 0, (size_t)N_NODES * sizeof(int), stream);

    prep_weights<<<320, 256, 0, stream>>>(Wq, Wk, Wv, Wf, Wo, WcatT, WoT);
    proj_mfma<<<521, 384, 0, stream>>>(feats, WcatT, bq, bk, bv, q, k, v);
    bucket_kernel<<<(N_EDGES + 255) / 256, 256, 0, stream>>>(esrc, edst, cnt, bucket);
    agg_fused<<<N_NODES / 4, 256, 0, stream>>>(q, k, v, cnt, bucket, wv);
    out_mfma<<<(N_NODES + 63) / 64, 256, 0, stream>>>(feats, wv, WoT, WcatT,
                                                      bo, bf, lg, lb, out);
}